// Round 1
// baseline (253.284 us; speedup 1.0000x reference)
//
#include <hip/hip_runtime.h>
#include <stdint.h>

#define NB 8
#define CIN 256
#define IC 128
#define NP 4096   // 64*64 positions per batch

typedef __attribute__((ext_vector_type(8))) short s8v;    // 8 bf16 (4 VGPRs)
typedef __attribute__((ext_vector_type(4))) short s4v;    // 4 bf16
typedef __attribute__((ext_vector_type(16))) float f16v;  // 32x32 MFMA acc
typedef __attribute__((ext_vector_type(4))) float f4v;

#define MFMA32(a, b, c) __builtin_amdgcn_mfma_f32_32x32x16_bf16(a, b, c, 0, 0, 0)

__device__ __forceinline__ unsigned short f2bf(float f) {
  union { float f; unsigned int u; } v; v.f = f;
  unsigned int u = v.u;
  return (unsigned short)((u + 0x7FFFu + ((u >> 16) & 1u)) >> 16);
}

typedef const unsigned int __attribute__((address_space(1))) gas_u32;
typedef unsigned int __attribute__((address_space(3))) las_u32;
__device__ __forceinline__ void gload_lds16(const void* g, void* l) {
  // async global->LDS DMA, 16B per lane; LDS dest = wave-uniform base + lane*16
  __builtin_amdgcn_global_load_lds((gas_u32*)g, (las_u32*)l, 16, 0, 0);
}

// ---------------------------------------------------------------------------
// Kernel 1: x[b,c,p] f32 -> xT[b,p,c] bf16 (LDS tile transpose, XOR swizzle)
// ---------------------------------------------------------------------------
__global__ __launch_bounds__(256) void k_transpose(const float* __restrict__ x,
                                                   unsigned short* __restrict__ xT) {
  __shared__ unsigned short T[64][72];  // swizzled cols: elem (c,p) at col p^(8*(c&7))
  const int t = threadIdx.x;
  const int b = blockIdx.z;
  const int c0 = blockIdx.y * 64;
  const int p0 = blockIdx.x * 64;
  const float* xp = x + (size_t)b * CIN * NP + (size_t)c0 * NP + p0;
  const int cl = t >> 4;
  const int p4 = (t & 15) * 4;
#pragma unroll
  for (int j = 0; j < 4; ++j) {
    const int c = cl + j * 16;
    const f4v v = *(const f4v*)(xp + (size_t)c * NP + p4);
    ushort4 u;
    u.x = f2bf(v[0]); u.y = f2bf(v[1]); u.z = f2bf(v[2]); u.w = f2bf(v[3]);
    *(ushort4*)&T[c][p4 ^ ((c & 7) * 8)] = u;
  }
  __syncthreads();
  const int p = t >> 2;
  unsigned short* dst = xT + ((size_t)b * NP + p0 + p) * CIN + c0;
#pragma unroll
  for (int half = 0; half < 2; ++half) {
    const int cg = (t & 3) + half * 4;
    alignas(16) unsigned short outv[8];
#pragma unroll
    for (int k = 0; k < 8; ++k)
      outv[k] = T[cg * 8 + k][p ^ (k * 8)];
    *(uint4*)(dst + cg * 8) = *(const uint4*)outv;
  }
}

// ---------------------------------------------------------------------------
// Kernel 2: three 1x1 convs. Q[b,q,128]=theta^T, K[b,k,128]=phi^T (bf16),
//           Vt[b,i,p]=g (natural layout == V^T for PV). MFMA 32x32x16.
// ---------------------------------------------------------------------------
__global__ __launch_bounds__(256) void k_conv3(const unsigned short* __restrict__ xT,
    const float* __restrict__ thw, const float* __restrict__ thb,
    const float* __restrict__ phw, const float* __restrict__ phb,
    const float* __restrict__ gw,  const float* __restrict__ gb,
    unsigned short* __restrict__ Qg, unsigned short* __restrict__ Kg,
    unsigned short* __restrict__ Vtg) {
  __shared__ unsigned short X[128 * 256];  // [p][c] bf16, 16B-chunk swizzle by 2*(p&15)
  const int t = threadIdx.x, lane = t & 63, wid = t >> 6;
  const int b = blockIdx.x >> 5;
  const int p0 = (blockIdx.x & 31) * 128;
  const int hl = lane >> 5;
  // stage x-tile [128p][256c] via DMA, pre-swizzled source chunks
  const unsigned short* srcb = xT + ((size_t)b * NP + p0) * CIN;
#pragma unroll
  for (int r = 0; r < 16; ++r) {
    const int ci = wid * 1024 + r * 64 + lane;
    const int p = ci >> 5, cc = ci & 31;
    gload_lds16(srcb + (size_t)p * CIN + 8 * (cc ^ (2 * (p & 15))),
                (char*)X + wid * 16384 + r * 1024);
  }
  const int orow = wid * 32 + (lane & 31);
  __syncthreads();

  for (int mat = 0; mat < 3; ++mat) {
    const float* W  = (mat == 0) ? thw : ((mat == 1) ? phw : gw);
    const float* Bs = (mat == 0) ? thb : ((mat == 1) ? phb : gb);
    s8v wf[16];
#pragma unroll
    for (int s = 0; s < 16; ++s) {
      const float* wp = W + (size_t)orow * CIN + hl * 8 + 16 * s;
      const f4v a = *(const f4v*)wp;
      const f4v c = *(const f4v*)(wp + 4);
      s8v f;
      f[0] = (short)f2bf(a[0]); f[1] = (short)f2bf(a[1]);
      f[2] = (short)f2bf(a[2]); f[3] = (short)f2bf(a[3]);
      f[4] = (short)f2bf(c[0]); f[5] = (short)f2bf(c[1]);
      f[6] = (short)f2bf(c[2]); f[7] = (short)f2bf(c[3]);
      wf[s] = f;
    }
    float br[16];
#pragma unroll
    for (int r = 0; r < 16; ++r)
      br[r] = Bs[wid * 32 + (r & 3) + 8 * (r >> 2) + 4 * hl];

    for (int nt = 0; nt < 4; ++nt) {
      const int p = (lane & 31) + nt * 32;
      f16v acc;
#pragma unroll
      for (int i = 0; i < 16; ++i) acc[i] = 0.f;
#pragma unroll
      for (int s = 0; s < 16; ++s) {
        const int cc0 = hl + 2 * s;
        const s8v xf = *(const s8v*)&X[p * 256 + 8 * (cc0 ^ (2 * (p & 15)))];
        acc = MFMA32(wf[s], xf, acc);
      }
      if (mat < 2) {
        unsigned short* G = ((mat == 0) ? Qg : Kg) + ((size_t)b * NP + p0 + p) * IC;
#pragma unroll
        for (int grp = 0; grp < 4; ++grp) {
          const int d0 = wid * 32 + 8 * grp + 4 * hl;
          ushort4 u;
          u.x = f2bf(acc[grp * 4 + 0] + br[grp * 4 + 0]);
          u.y = f2bf(acc[grp * 4 + 1] + br[grp * 4 + 1]);
          u.z = f2bf(acc[grp * 4 + 2] + br[grp * 4 + 2]);
          u.w = f2bf(acc[grp * 4 + 3] + br[grp * 4 + 3]);
          *(ushort4*)(G + d0) = u;
        }
      } else {
        unsigned short* G = Vtg + (size_t)b * IC * NP + p0 + p;
#pragma unroll
        for (int r = 0; r < 16; ++r) {
          const int row = wid * 32 + (r & 3) + 8 * (r >> 2) + 4 * hl;
          G[(size_t)row * NP] = f2bf(acc[r] + br[r]);
        }
      }
    }
  }
}

// ---------------------------------------------------------------------------
// Kernel 3: flash attention per (batch, 128-q block). 4 waves x 32 q.
// Swapped QK^T (S^T = K*Q^T) -> per-lane softmax; zero-shuffle PV via
// matched k-permutation on V fragments. KVBLK=64, single-buffered LDS.
// ---------------------------------------------------------------------------
__global__ __launch_bounds__(256) void k_attn(const unsigned short* __restrict__ Qg,
    const unsigned short* __restrict__ Kg, const unsigned short* __restrict__ Vtg,
    unsigned short* __restrict__ Og) {
  __shared__ unsigned short Klds[64 * 128];  // [kv][d], 16B-chunk swizzle by (kv&15)
  __shared__ unsigned short Vlds[128 * 68];  // [d][kv], rows padded to 136B (17 dw)
  const int t = threadIdx.x, lane = t & 63, wid = t >> 6;
  const int b = blockIdx.y;
  const int q0 = blockIdx.x * 128;
  const int hl = lane >> 5;
  const int q = q0 + wid * 32 + (lane & 31);
  const unsigned short* Qp = Qg + (size_t)b * NP * IC + (size_t)q * IC;
  s8v qf[8];
#pragma unroll
  for (int s = 0; s < 8; ++s)
    qf[s] = *(const s8v*)(Qp + hl * 8 + 16 * s);
  f16v oa[4];
#pragma unroll
  for (int dt = 0; dt < 4; ++dt)
#pragma unroll
    for (int i = 0; i < 16; ++i) oa[dt][i] = 0.f;
  float m = -3.0e38f, lsum = 0.f;
  const unsigned short* Kb = Kg + (size_t)b * NP * IC;
  const unsigned short* Vb = Vtg + (size_t)b * IC * NP;

  for (int it = 0; it < 64; ++it) {
    const int kv0 = it * 64;
    // stage K tile [64][128] via DMA (pre-swizzled source chunks)
#pragma unroll
    for (int r = 0; r < 4; ++r) {
      const int ci = wid * 256 + r * 64 + lane;
      const int kv = ci >> 4, cc = ci & 15;
      gload_lds16(Kb + (size_t)(kv0 + kv) * IC + 8 * (cc ^ (kv & 15)),
                  (char*)Klds + wid * 4096 + r * 1024);
    }
    // stage V tile [128][64] via regs into padded rows (coalesced 128B reads)
    {
      const int ch = t & 7;
      const int dbase = t >> 3;
      const unsigned short* vs = Vb + kv0 + ch * 8;
#pragma unroll
      for (int j = 0; j < 4; ++j) {
        const int dd = dbase + j * 32;
        const uint4 v = *(const uint4*)(vs + (size_t)dd * NP);
        uint2* w0 = (uint2*)&Vlds[dd * 68 + ch * 8];
        w0[0] = make_uint2(v.x, v.y);
        w0[1] = make_uint2(v.z, v.w);
      }
    }
    __syncthreads();
    // S^T[k][q] = sum_d K[k][d] * Q[q][d]
    f16v st0, st1;
#pragma unroll
    for (int i = 0; i < 16; ++i) { st0[i] = 0.f; st1[i] = 0.f; }
#pragma unroll
    for (int s = 0; s < 8; ++s) {
      const int cc0 = hl + 2 * s;
      const int kva = lane & 31;
      const s8v ka  = *(const s8v*)&Klds[kva * 128 + 8 * (cc0 ^ (kva & 15))];
      const s8v kb2 = *(const s8v*)&Klds[(kva + 32) * 128 + 8 * (cc0 ^ (kva & 15))];
      st0 = MFMA32(ka, qf[s], st0);
      st1 = MFMA32(kb2, qf[s], st1);
    }
    // online softmax: column q split across lane and lane^32
    float pmax = st0[0];
#pragma unroll
    for (int i = 1; i < 16; ++i) pmax = fmaxf(pmax, st0[i]);
#pragma unroll
    for (int i = 0; i < 16; ++i) pmax = fmaxf(pmax, st1[i]);
    pmax = fmaxf(pmax, __shfl_xor(pmax, 32));
    const float mn = fmaxf(m, pmax);
    const float sc = __expf(m - mn);
    m = mn;
    float psum = 0.f;
#pragma unroll
    for (int i = 0; i < 16; ++i) { st0[i] = __expf(st0[i] - mn); psum += st0[i]; }
#pragma unroll
    for (int i = 0; i < 16; ++i) { st1[i] = __expf(st1[i] - mn); psum += st1[i]; }
    psum += __shfl_xor(psum, 32);
    lsum = lsum * sc + psum;
#pragma unroll
    for (int dt = 0; dt < 4; ++dt)
#pragma unroll
      for (int i = 0; i < 16; ++i) oa[dt][i] *= sc;
    // P -> bf16 B-fragments (D-reg order IS the k-permutation)
    s8v pf0, pf1, pf2, pf3;
#pragma unroll
    for (int i = 0; i < 8; ++i) {
      pf0[i] = (short)f2bf(st0[i]);
      pf1[i] = (short)f2bf(st0[8 + i]);
      pf2[i] = (short)f2bf(st1[i]);
      pf3[i] = (short)f2bf(st1[8 + i]);
    }
    // O^T[d][q] += V^T[d][k] * P^T[k][q]; V frags use matching k-pattern:
    // k(i) = (i&3) + 8*(i>>2) + 4*hl + 16*s2 + 32*tt
#pragma unroll
    for (int ks = 0; ks < 4; ++ks) {
      const int k0 = 4 * hl + 16 * (ks & 1) + 32 * (ks >> 1);
      const s8v pcur = (ks == 0) ? pf0 : ((ks == 1) ? pf1 : ((ks == 2) ? pf2 : pf3));
#pragma unroll
      for (int dt = 0; dt < 4; ++dt) {
        const int d = dt * 32 + (lane & 31);
        const s4v va = *(const s4v*)&Vlds[d * 68 + k0];
        const s4v vb = *(const s4v*)&Vlds[d * 68 + k0 + 8];
        s8v vf;
        vf[0] = va[0]; vf[1] = va[1]; vf[2] = va[2]; vf[3] = va[3];
        vf[4] = vb[0]; vf[5] = vb[1]; vf[6] = vb[2]; vf[7] = vb[3];
        oa[dt] = MFMA32(vf, pcur, oa[dt]);
      }
    }
    __syncthreads();
  }
  // epilogue: normalize and store O[b][q][d] bf16
  const float inv = 1.0f / lsum;
  unsigned short* Op = Og + (size_t)b * NP * IC + (size_t)q * IC;
#pragma unroll
  for (int dt = 0; dt < 4; ++dt) {
#pragma unroll
    for (int grp = 0; grp < 4; ++grp) {
      const int d0 = dt * 32 + 8 * grp + 4 * hl;
      ushort4 u;
      u.x = f2bf(oa[dt][grp * 4 + 0] * inv);
      u.y = f2bf(oa[dt][grp * 4 + 1] * inv);
      u.z = f2bf(oa[dt][grp * 4 + 2] * inv);
      u.w = f2bf(oa[dt][grp * 4 + 3] * inv);
      *(ushort4*)(Op + d0) = u;
    }
  }
}

// ---------------------------------------------------------------------------
// Kernel 4: out[b,o,p] = W_w[o,:] . y[b,:,p] + W_b[o] + x[b,o,p]  (fp32 out)
// ---------------------------------------------------------------------------
__global__ __launch_bounds__(256) void k_out(const unsigned short* __restrict__ Og,
    const float* __restrict__ Ww, const float* __restrict__ Wb,
    const float* __restrict__ x, float* __restrict__ out) {
  __shared__ unsigned short Y[128 * 128];  // [p][i], 16B-chunk swizzle by (p&15)
  const int t = threadIdx.x, lane = t & 63, wid = t >> 6;
  const int b = blockIdx.x >> 5;
  const int p0 = (blockIdx.x & 31) * 128;
  const int mt = blockIdx.y;
  const int hl = lane >> 5;
  const unsigned short* srcb = Og + ((size_t)b * NP + p0) * IC;
#pragma unroll
  for (int r = 0; r < 8; ++r) {
    const int ci = wid * 512 + r * 64 + lane;
    const int p = ci >> 4, cc = ci & 15;
    gload_lds16(srcb + (size_t)p * IC + 8 * (cc ^ (p & 15)),
                (char*)Y + wid * 8192 + r * 1024);
  }
  const int orow = mt * 128 + wid * 32 + (lane & 31);
  s8v wf[8];
#pragma unroll
  for (int s = 0; s < 8; ++s) {
    const float* wp = Ww + (size_t)orow * IC + hl * 8 + 16 * s;
    const f4v a = *(const f4v*)wp;
    const f4v c = *(const f4v*)(wp + 4);
    s8v f;
    f[0] = (short)f2bf(a[0]); f[1] = (short)f2bf(a[1]);
    f[2] = (short)f2bf(a[2]); f[3] = (short)f2bf(a[3]);
    f[4] = (short)f2bf(c[0]); f[5] = (short)f2bf(c[1]);
    f[6] = (short)f2bf(c[2]); f[7] = (short)f2bf(c[3]);
    wf[s] = f;
  }
  float br[16];
#pragma unroll
  for (int r = 0; r < 16; ++r)
    br[r] = Wb[mt * 128 + wid * 32 + (r & 3) + 8 * (r >> 2) + 4 * hl];
  __syncthreads();
  for (int nt = 0; nt < 4; ++nt) {
    const int p = (lane & 31) + nt * 32;
    f16v acc;
#pragma unroll
    for (int i = 0; i < 16; ++i) acc[i] = 0.f;
#pragma unroll
    for (int s = 0; s < 8; ++s) {
      const int cc0 = hl + 2 * s;
      const s8v yf = *(const s8v*)&Y[p * 128 + 8 * (cc0 ^ (p & 15))];
      acc = MFMA32(wf[s], yf, acc);
    }
    const size_t pidx = (size_t)b * CIN * NP + (size_t)(p0 + p);
#pragma unroll
    for (int r = 0; r < 16; ++r) {
      const int row = mt * 128 + wid * 32 + (r & 3) + 8 * (r >> 2) + 4 * hl;
      const size_t idx = pidx + (size_t)row * NP;
      out[idx] = acc[r] + br[r] + x[idx];
    }
  }
}

// ---------------------------------------------------------------------------
extern "C" void kernel_launch(void* const* d_in, const int* in_sizes, int n_in,
                              void* d_out, int out_size, void* d_ws, size_t ws_size,
                              hipStream_t stream) {
  const float* x   = (const float*)d_in[0];
  const float* gw  = (const float*)d_in[1];
  const float* gb  = (const float*)d_in[2];
  const float* thw = (const float*)d_in[3];
  const float* thb = (const float*)d_in[4];
  const float* phw = (const float*)d_in[5];
  const float* phb = (const float*)d_in[6];
  const float* Ww  = (const float*)d_in[7];
  const float* Wb  = (const float*)d_in[8];
  float* out = (float*)d_out;

  // workspace layout (ushorts): xT 8.39M | Q 4.19M | K 4.19M | Vt 4.19M | O 4.19M
  unsigned short* ws  = (unsigned short*)d_ws;
  unsigned short* xT  = ws;
  unsigned short* Qg  = ws + 8388608;
  unsigned short* Kg  = Qg + 4194304;
  unsigned short* Vtg = Kg + 4194304;
  unsigned short* Og  = Vtg + 4194304;

  k_transpose<<<dim3(64, 4, 8), dim3(256), 0, stream>>>(x, xT);
  k_conv3<<<dim3(256), dim3(256), 0, stream>>>(xT, thw, thb, phw, phb, gw, gb,
                                               Qg, Kg, Vtg);
  k_attn<<<dim3(32, 8), dim3(256), 0, stream>>>(Qg, Kg, Vtg, Og);
  k_out<<<dim3(256, 2), dim3(256), 0, stream>>>(Og, Ww, Wb, x, out);
}

// Round 2
// 196.186 us; speedup vs baseline: 1.2910x; 1.2910x over previous
//
#include <hip/hip_runtime.h>
#include <hip/hip_bf16.h>
#include <stdint.h>

#define NB 8
#define CIN 256
#define IC 128
#define NP 4096   // 64*64 positions per batch

typedef __attribute__((ext_vector_type(8))) short s8v;    // 8 bf16 (4 VGPRs)
typedef __attribute__((ext_vector_type(4))) short s4v;    // 4 bf16
typedef __attribute__((ext_vector_type(16))) float f16v;  // 32x32 MFMA acc
typedef __attribute__((ext_vector_type(4))) float f4v;

#define MFMA32(a, b, c) __builtin_amdgcn_mfma_f32_32x32x16_bf16(a, b, c, 0, 0, 0)

__device__ __forceinline__ unsigned short f2bf(float f) {
  union { float f; unsigned int u; } v; v.f = f;
  unsigned int u = v.u;
  return (unsigned short)((u + 0x7FFFu + ((u >> 16) & 1u)) >> 16);
}

// hw-converted RNE f32->bf16 (compiler emits v_cvt_pk_bf16_f32 when paired)
__device__ __forceinline__ unsigned short f2bf_h(float f) {
  __hip_bfloat16 h = __float2bfloat16(f);
  union { __hip_bfloat16 h; unsigned short u; } cv; cv.h = h;
  return cv.u;
}

typedef const unsigned int __attribute__((address_space(1))) gas_u32;
typedef unsigned int __attribute__((address_space(3))) las_u32;
__device__ __forceinline__ void gload_lds16(const void* g, void* l) {
  // async global->LDS DMA, 16B per lane; LDS dest = wave-uniform base + lane*16
  __builtin_amdgcn_global_load_lds((gas_u32*)g, (las_u32*)l, 16, 0, 0);
}

// ---------------------------------------------------------------------------
// Kernel 1: x[b,c,p] f32 -> xT[b,p,c] bf16 (LDS tile transpose, XOR swizzle)
// ---------------------------------------------------------------------------
__global__ __launch_bounds__(256) void k_transpose(const float* __restrict__ x,
                                                   unsigned short* __restrict__ xT) {
  __shared__ unsigned short T[64][72];  // swizzled cols: elem (c,p) at col p^(8*(c&7))
  const int t = threadIdx.x;
  const int b = blockIdx.z;
  const int c0 = blockIdx.y * 64;
  const int p0 = blockIdx.x * 64;
  const float* xp = x + (size_t)b * CIN * NP + (size_t)c0 * NP + p0;
  const int cl = t >> 4;
  const int p4 = (t & 15) * 4;
#pragma unroll
  for (int j = 0; j < 4; ++j) {
    const int c = cl + j * 16;
    const f4v v = *(const f4v*)(xp + (size_t)c * NP + p4);
    ushort4 u;
    u.x = f2bf(v[0]); u.y = f2bf(v[1]); u.z = f2bf(v[2]); u.w = f2bf(v[3]);
    *(ushort4*)&T[c][p4 ^ ((c & 7) * 8)] = u;
  }
  __syncthreads();
  const int p = t >> 2;
  unsigned short* dst = xT + ((size_t)b * NP + p0 + p) * CIN + c0;
#pragma unroll
  for (int half = 0; half < 2; ++half) {
    const int cg = (t & 3) + half * 4;
    alignas(16) unsigned short outv[8];
#pragma unroll
    for (int k = 0; k < 8; ++k)
      outv[k] = T[cg * 8 + k][p ^ (k * 8)];
    *(uint4*)(dst + cg * 8) = *(const uint4*)outv;
  }
}

// ---------------------------------------------------------------------------
// Kernel 2: three 1x1 convs. Q[b,q,128]=theta^T, K[b,k,128]=phi^T (bf16),
//           Vt[b,i,p]=g (natural layout == V^T for PV). MFMA 32x32x16.
// ---------------------------------------------------------------------------
__global__ __launch_bounds__(256) void k_conv3(const unsigned short* __restrict__ xT,
    const float* __restrict__ thw, const float* __restrict__ thb,
    const float* __restrict__ phw, const float* __restrict__ phb,
    const float* __restrict__ gw,  const float* __restrict__ gb,
    unsigned short* __restrict__ Qg, unsigned short* __restrict__ Kg,
    unsigned short* __restrict__ Vtg) {
  __shared__ unsigned short X[128 * 256];  // [p][c] bf16, 16B-chunk swizzle by 2*(p&15)
  const int t = threadIdx.x, lane = t & 63, wid = t >> 6;
  const int b = blockIdx.x >> 5;
  const int p0 = (blockIdx.x & 31) * 128;
  const int hl = lane >> 5;
  // stage x-tile [128p][256c] via DMA, pre-swizzled source chunks
  const unsigned short* srcb = xT + ((size_t)b * NP + p0) * CIN;
#pragma unroll
  for (int r = 0; r < 16; ++r) {
    const int ci = wid * 1024 + r * 64 + lane;
    const int p = ci >> 5, cc = ci & 31;
    gload_lds16(srcb + (size_t)p * CIN + 8 * (cc ^ (2 * (p & 15))),
                (char*)X + wid * 16384 + r * 1024);
  }
  const int orow = wid * 32 + (lane & 31);
  __syncthreads();

  for (int mat = 0; mat < 3; ++mat) {
    const float* W  = (mat == 0) ? thw : ((mat == 1) ? phw : gw);
    const float* Bs = (mat == 0) ? thb : ((mat == 1) ? phb : gb);
    s8v wf[16];
#pragma unroll
    for (int s = 0; s < 16; ++s) {
      const float* wp = W + (size_t)orow * CIN + hl * 8 + 16 * s;
      const f4v a = *(const f4v*)wp;
      const f4v c = *(const f4v*)(wp + 4);
      s8v f;
      f[0] = (short)f2bf(a[0]); f[1] = (short)f2bf(a[1]);
      f[2] = (short)f2bf(a[2]); f[3] = (short)f2bf(a[3]);
      f[4] = (short)f2bf(c[0]); f[5] = (short)f2bf(c[1]);
      f[6] = (short)f2bf(c[2]); f[7] = (short)f2bf(c[3]);
      wf[s] = f;
    }
    float br[16];
#pragma unroll
    for (int r = 0; r < 16; ++r)
      br[r] = Bs[wid * 32 + (r & 3) + 8 * (r >> 2) + 4 * hl];

    for (int nt = 0; nt < 4; ++nt) {
      const int p = (lane & 31) + nt * 32;
      f16v acc;
#pragma unroll
      for (int i = 0; i < 16; ++i) acc[i] = 0.f;
#pragma unroll
      for (int s = 0; s < 16; ++s) {
        const int cc0 = hl + 2 * s;
        const s8v xf = *(const s8v*)&X[p * 256 + 8 * (cc0 ^ (2 * (p & 15)))];
        acc = MFMA32(wf[s], xf, acc);
      }
      if (mat < 2) {
        unsigned short* G = ((mat == 0) ? Qg : Kg) + ((size_t)b * NP + p0 + p) * IC;
#pragma unroll
        for (int grp = 0; grp < 4; ++grp) {
          const int d0 = wid * 32 + 8 * grp + 4 * hl;
          ushort4 u;
          u.x = f2bf(acc[grp * 4 + 0] + br[grp * 4 + 0]);
          u.y = f2bf(acc[grp * 4 + 1] + br[grp * 4 + 1]);
          u.z = f2bf(acc[grp * 4 + 2] + br[grp * 4 + 2]);
          u.w = f2bf(acc[grp * 4 + 3] + br[grp * 4 + 3]);
          *(ushort4*)(G + d0) = u;
        }
      } else {
        unsigned short* G = Vtg + (size_t)b * IC * NP + p0 + p;
#pragma unroll
        for (int r = 0; r < 16; ++r) {
          const int row = wid * 32 + (r & 3) + 8 * (r >> 2) + 4 * hl;
          G[(size_t)row * NP] = f2bf(acc[r] + br[r]);
        }
      }
    }
  }
}

// ---------------------------------------------------------------------------
// Kernel 3: flash attention per (batch, 128-q block). 4 waves x 32 q.
// Pipelined: K double-buffered via DMA prefetch, V reg-staged (T14 split),
// XCD-aligned batches (T1), exp2-domain softmax with defer-rescale (T13),
// setprio around MFMA (T5). 2 barriers/iter, LDS 50 KB.
// ---------------------------------------------------------------------------
__global__ __launch_bounds__(256) void k_attn(const unsigned short* __restrict__ Qg,
    const unsigned short* __restrict__ Kg, const unsigned short* __restrict__ Vtg,
    unsigned short* __restrict__ Og) {
  __shared__ unsigned short Klds[2][64 * 128];  // [buf][kv][d], chunk-swizzled by (kv&15)
  __shared__ unsigned short Vlds[128 * 68];     // [d][kv], rows padded to 136B
  const int t = threadIdx.x, lane = t & 63, wid = t >> 6;
  const int bid = blockIdx.x;
  const int b = bid & 7;               // XCD-aligned: one batch per XCD L2
  const int q0 = (bid >> 3) * 128;
  const int hl = lane >> 5;
  const int q = q0 + wid * 32 + (lane & 31);
  // Q fragment, pre-scaled by log2(e): softmax runs in exp2 domain
  const unsigned short* Qp = Qg + (size_t)b * NP * IC + (size_t)q * IC;
  s8v qf[8];
#pragma unroll
  for (int s = 0; s < 8; ++s) {
    const s8v v = *(const s8v*)(Qp + hl * 8 + 16 * s);
    s8v r;
#pragma unroll
    for (int j = 0; j < 8; ++j) {
      union { unsigned int u; float f; } cv;
      cv.u = ((unsigned int)(unsigned short)v[j]) << 16;
      r[j] = (short)f2bf_h(cv.f * 1.44269504f);
    }
    qf[s] = r;
  }
  f16v oa[4];
#pragma unroll
  for (int dt = 0; dt < 4; ++dt)
#pragma unroll
    for (int i = 0; i < 16; ++i) oa[dt][i] = 0.f;
  float m = -3.0e38f, lsum = 0.f;
  const unsigned short* Kb = Kg + (size_t)b * NP * IC;
  const unsigned short* Vb = Vtg + (size_t)b * IC * NP;
  const int ch = t & 7, dbase = t >> 3;

  uint4 vreg[4];
  // ---- prologue: stage tile 0 ----
#pragma unroll
  for (int r = 0; r < 4; ++r) {
    const int ci = wid * 256 + r * 64 + lane;
    const int kv = ci >> 4, cc = ci & 15;
    gload_lds16(Kb + (size_t)kv * IC + 8 * (cc ^ (kv & 15)),
                (char*)&Klds[0][0] + wid * 4096 + r * 1024);
  }
  {
    const unsigned short* vs = Vb + ch * 8;
#pragma unroll
    for (int j = 0; j < 4; ++j)
      vreg[j] = *(const uint4*)(vs + (size_t)(dbase + j * 32) * NP);
  }
#pragma unroll
  for (int j = 0; j < 4; ++j) {
    uint2* w0 = (uint2*)&Vlds[(dbase + j * 32) * 68 + ch * 8];
    w0[0] = make_uint2(vreg[j].x, vreg[j].y);
    w0[1] = make_uint2(vreg[j].z, vreg[j].w);
  }
  __syncthreads();

  for (int it = 0; it < 64; ++it) {
    const int cur = it & 1;
    // ---- issue next-tile staging first (overlaps with compute below) ----
    if (it < 63) {
      const int kv0n = (it + 1) * 64;
      const unsigned short* vs = Vb + kv0n + ch * 8;
#pragma unroll
      for (int j = 0; j < 4; ++j)
        vreg[j] = *(const uint4*)(vs + (size_t)(dbase + j * 32) * NP);
#pragma unroll
      for (int r = 0; r < 4; ++r) {
        const int ci = wid * 256 + r * 64 + lane;
        const int kv = ci >> 4, cc = ci & 15;
        gload_lds16(Kb + (size_t)(kv0n + kv) * IC + 8 * (cc ^ (kv & 15)),
                    (char*)&Klds[cur ^ 1][0] + wid * 4096 + r * 1024);
      }
    }
    // ---- S^T[k][q] = K * Q^T (log2e-scaled) ----
    f16v st0, st1;
#pragma unroll
    for (int i = 0; i < 16; ++i) { st0[i] = 0.f; st1[i] = 0.f; }
    __builtin_amdgcn_s_setprio(1);
#pragma unroll
    for (int s = 0; s < 8; ++s) {
      const int cc0 = hl + 2 * s;
      const int kva = lane & 31;
      const s8v ka  = *(const s8v*)&Klds[cur][kva * 128 + 8 * (cc0 ^ (kva & 15))];
      const s8v kb2 = *(const s8v*)&Klds[cur][(kva + 32) * 128 + 8 * (cc0 ^ (kva & 15))];
      st0 = MFMA32(ka, qf[s], st0);
      st1 = MFMA32(kb2, qf[s], st1);
    }
    __builtin_amdgcn_s_setprio(0);
    // ---- online softmax (exp2 domain, defer-rescale THR=8) ----
    float pmax = st0[0];
#pragma unroll
    for (int i = 1; i < 16; ++i) pmax = fmaxf(pmax, st0[i]);
#pragma unroll
    for (int i = 0; i < 16; ++i) pmax = fmaxf(pmax, st1[i]);
    pmax = fmaxf(pmax, __shfl_xor(pmax, 32));
    if (__any(pmax > m + 8.f)) {
      const float mn = fmaxf(m, pmax);
      const float sc = __builtin_amdgcn_exp2f(m - mn);
      m = mn;
      lsum *= sc;
#pragma unroll
      for (int dt = 0; dt < 4; ++dt)
#pragma unroll
        for (int i = 0; i < 16; ++i) oa[dt][i] *= sc;
    }
    float psum = 0.f;
#pragma unroll
    for (int i = 0; i < 16; ++i) { st0[i] = __builtin_amdgcn_exp2f(st0[i] - m); psum += st0[i]; }
#pragma unroll
    for (int i = 0; i < 16; ++i) { st1[i] = __builtin_amdgcn_exp2f(st1[i] - m); psum += st1[i]; }
    psum += __shfl_xor(psum, 32);
    lsum += psum;
    // P -> bf16 B-fragments (D-reg order IS the k-permutation)
    s8v pf0, pf1, pf2, pf3;
#pragma unroll
    for (int i = 0; i < 8; ++i) {
      pf0[i] = (short)f2bf_h(st0[i]);
      pf1[i] = (short)f2bf_h(st0[8 + i]);
      pf2[i] = (short)f2bf_h(st1[i]);
      pf3[i] = (short)f2bf_h(st1[8 + i]);
    }
    // ---- O^T[d][q] += V^T[d][k] * P^T[k][q], matched k-permutation ----
    __builtin_amdgcn_s_setprio(1);
#pragma unroll
    for (int ks = 0; ks < 4; ++ks) {
      const int k0 = 4 * hl + 16 * (ks & 1) + 32 * (ks >> 1);
      const s8v pcur = (ks == 0) ? pf0 : ((ks == 1) ? pf1 : ((ks == 2) ? pf2 : pf3));
#pragma unroll
      for (int dt = 0; dt < 4; ++dt) {
        const int d = dt * 32 + (lane & 31);
        const s4v va = *(const s4v*)&Vlds[d * 68 + k0];
        const s4v vb2 = *(const s4v*)&Vlds[d * 68 + k0 + 8];
        s8v vf;
        vf[0] = va[0]; vf[1] = va[1]; vf[2] = va[2]; vf[3] = va[3];
        vf[4] = vb2[0]; vf[5] = vb2[1]; vf[6] = vb2[2]; vf[7] = vb2[3];
        oa[dt] = MFMA32(vf, pcur, oa[dt]);
      }
    }
    __builtin_amdgcn_s_setprio(0);
    __syncthreads();  // all PV reads of Vlds done; K DMA drained here too
    if (it < 63) {
#pragma unroll
      for (int j = 0; j < 4; ++j) {
        uint2* w0 = (uint2*)&Vlds[(dbase + j * 32) * 68 + ch * 8];
        w0[0] = make_uint2(vreg[j].x, vreg[j].y);
        w0[1] = make_uint2(vreg[j].z, vreg[j].w);
      }
    }
    __syncthreads();  // V tile t+1 visible to all
  }
  // epilogue: normalize and store O[b][q][d] bf16
  const float inv = 1.0f / lsum;
  unsigned short* Op = Og + (size_t)b * NP * IC + (size_t)q * IC;
#pragma unroll
  for (int dt = 0; dt < 4; ++dt) {
#pragma unroll
    for (int grp = 0; grp < 4; ++grp) {
      const int d0 = dt * 32 + 8 * grp + 4 * hl;
      ushort4 u;
      u.x = f2bf_h(oa[dt][grp * 4 + 0] * inv);
      u.y = f2bf_h(oa[dt][grp * 4 + 1] * inv);
      u.z = f2bf_h(oa[dt][grp * 4 + 2] * inv);
      u.w = f2bf_h(oa[dt][grp * 4 + 3] * inv);
      *(ushort4*)(Op + d0) = u;
    }
  }
}

// ---------------------------------------------------------------------------
// Kernel 4: out[b,o,p] = W_w[o,:] . y[b,:,p] + W_b[o] + x[b,o,p]  (fp32 out)
// ---------------------------------------------------------------------------
__global__ __launch_bounds__(256) void k_out(const unsigned short* __restrict__ Og,
    const float* __restrict__ Ww, const float* __restrict__ Wb,
    const float* __restrict__ x, float* __restrict__ out) {
  __shared__ unsigned short Y[128 * 128];  // [p][i], 16B-chunk swizzle by (p&15)
  const int t = threadIdx.x, lane = t & 63, wid = t >> 6;
  const int b = blockIdx.x >> 5;
  const int p0 = (blockIdx.x & 31) * 128;
  const int mt = blockIdx.y;
  const int hl = lane >> 5;
  const unsigned short* srcb = Og + ((size_t)b * NP + p0) * IC;
#pragma unroll
  for (int r = 0; r < 8; ++r) {
    const int ci = wid * 512 + r * 64 + lane;
    const int p = ci >> 4, cc = ci & 15;
    gload_lds16(srcb + (size_t)p * IC + 8 * (cc ^ (p & 15)),
                (char*)Y + wid * 8192 + r * 1024);
  }
  const int orow = mt * 128 + wid * 32 + (lane & 31);
  s8v wf[8];
#pragma unroll
  for (int s = 0; s < 8; ++s) {
    const float* wp = Ww + (size_t)orow * IC + hl * 8 + 16 * s;
    const f4v a = *(const f4v*)wp;
    const f4v c = *(const f4v*)(wp + 4);
    s8v f;
    f[0] = (short)f2bf(a[0]); f[1] = (short)f2bf(a[1]);
    f[2] = (short)f2bf(a[2]); f[3] = (short)f2bf(a[3]);
    f[4] = (short)f2bf(c[0]); f[5] = (short)f2bf(c[1]);
    f[6] = (short)f2bf(c[2]); f[7] = (short)f2bf(c[3]);
    wf[s] = f;
  }
  float br[16];
#pragma unroll
  for (int r = 0; r < 16; ++r)
    br[r] = Wb[mt * 128 + wid * 32 + (r & 3) + 8 * (r >> 2) + 4 * hl];
  __syncthreads();
  for (int nt = 0; nt < 4; ++nt) {
    const int p = (lane & 31) + nt * 32;
    f16v acc;
#pragma unroll
    for (int i = 0; i < 16; ++i) acc[i] = 0.f;
#pragma unroll
    for (int s = 0; s < 8; ++s) {
      const int cc0 = hl + 2 * s;
      const s8v yf = *(const s8v*)&Y[p * 128 + 8 * (cc0 ^ (p & 15))];
      acc = MFMA32(wf[s], yf, acc);
    }
    const size_t pidx = (size_t)b * CIN * NP + (size_t)(p0 + p);
#pragma unroll
    for (int r = 0; r < 16; ++r) {
      const int row = mt * 128 + wid * 32 + (r & 3) + 8 * (r >> 2) + 4 * hl;
      const size_t idx = pidx + (size_t)row * NP;
      out[idx] = acc[r] + br[r] + x[idx];
    }
  }
}

// ---------------------------------------------------------------------------
extern "C" void kernel_launch(void* const* d_in, const int* in_sizes, int n_in,
                              void* d_out, int out_size, void* d_ws, size_t ws_size,
                              hipStream_t stream) {
  const float* x   = (const float*)d_in[0];
  const float* gw  = (const float*)d_in[1];
  const float* gb  = (const float*)d_in[2];
  const float* thw = (const float*)d_in[3];
  const float* thb = (const float*)d_in[4];
  const float* phw = (const float*)d_in[5];
  const float* phb = (const float*)d_in[6];
  const float* Ww  = (const float*)d_in[7];
  const float* Wb  = (const float*)d_in[8];
  float* out = (float*)d_out;

  // workspace layout (ushorts): xT 8.39M | Q 4.19M | K 4.19M | Vt 4.19M | O 4.19M
  unsigned short* ws  = (unsigned short*)d_ws;
  unsigned short* xT  = ws;
  unsigned short* Qg  = ws + 8388608;
  unsigned short* Kg  = Qg + 4194304;
  unsigned short* Vtg = Kg + 4194304;
  unsigned short* Og  = Vtg + 4194304;

  k_transpose<<<dim3(64, 4, 8), dim3(256), 0, stream>>>(x, xT);
  k_conv3<<<dim3(256), dim3(256), 0, stream>>>(xT, thw, thb, phw, phb, gw, gb,
                                               Qg, Kg, Vtg);
  k_attn<<<dim3(256), dim3(256), 0, stream>>>(Qg, Kg, Vtg, Og);
  k_out<<<dim3(256, 2), dim3(256), 0, stream>>>(Og, Ww, Wb, x, out);
}